// Round 1
// 169.336 us; speedup vs baseline: 1.0020x; 1.0020x over previous
//
#include <hip/hip_runtime.h>
#include <stdint.h>

typedef unsigned int u32;

using i32x8 = __attribute__((ext_vector_type(8))) int;
using f32x4 = __attribute__((ext_vector_type(4))) float;

typedef __attribute__((address_space(1))) const void as1_void;
typedef __attribute__((address_space(3))) void       as3_void;

#define NROWS 32768   // B*H*W*D / 256 rows after reshape(-1,256)
#define NDIM  256
#define KCODES 8192
#define ND_TOT 8388608
#define CBSCALE 8192.0f   // lifts codebook (+-1.2e-4) into e4m3 range; argmax invariant

// ---------------- prep: cb -> fp8 (x8192), + zero the loss slot ----------------
__global__ __launch_bounds__(256) void prep_cb8_kernel(const float* __restrict__ cb,
                                                       u32* __restrict__ cbb8,
                                                       float* __restrict__ loss) {
    if (blockIdx.x == 0 && threadIdx.x == 0) loss[0] = 0.f;   // out re-poisoned each call
    int base = (blockIdx.x * 256 + threadIdx.x) * 16;
    uint4 o;
    #pragma unroll
    for (int q = 0; q < 4; q++) {
        float4 v = *(const float4*)(cb + base + q * 4);
        int r = __builtin_amdgcn_cvt_pk_fp8_f32(v.x * CBSCALE, v.y * CBSCALE, 0, false);
        r     = __builtin_amdgcn_cvt_pk_fp8_f32(v.z * CBSCALE, v.w * CBSCALE, r, true);
        ((u32*)&o)[q] = (u32)r;
    }
    *(uint4*)((char*)cbb8 + base) = o;   // fp8: byte index == element index
}

// ---------------- fully fused: GEMM + argmax + gather + ST + loss ----------------
// Block = 64 m-rows x ALL 8192 codes; grid 512 = 2 blocks/CU. Each of the 4
// waves holds ALL 64 rows (A replicated) and owns a private codebook QUARTER
// streamed through a private 4-slot 16KB LDS ring. Chunk = 32 codes x 128 K
// = 4 KB = 4 DMAs; staging runs THREE chunks ahead, sync = s_waitcnt
// vmcnt(12) only (in-order VMEM retirement: the wait retires exactly the
// chunk about to be consumed, leaving 3 chunks / 12 DMAs in flight). This
// replaces the previous 2-slot / 1-chunk-deep ring whose vmcnt(8) wait
// could not cover the L2->LDS DMA round-trip (~29% on every pipe, 3750
// cyc/CU per half-step vs ~1170 required). ZERO s_barrier in the loop.
// acc-init eliminated via bias-C on the kh=0 MFMA (+2048 => scores positive
// => float order == int order). LDS geometry = R7-verified 0-conflict
// 2-plane layout scaled to 32-row chunks (plane = 2KB of [32 rows x 64B],
// read addr rb*64 + ((quad^((rb>>1)&3))<<4), planes +0/+2048). Tail chunks
// clamp to a re-stage of chunk 127 into dead slots (keeps vmcnt uniform).
// After the loop: one __syncthreads, merge 4 quarter-keys in LDS, gather
// fp32 codebook rows, straight-through write + one atomicAdd loss partial.
__global__ __launch_bounds__(256, 2) void vq_fused_kernel(const float* __restrict__ z,
                                                          const float* __restrict__ cb,
                                                          const u32* __restrict__ cbb8,
                                                          float* __restrict__ out) {
    __shared__ __align__(16) char Bs[4][4][4096];    // [wave][slot] private rings
    __shared__ u32 keys_lds[4][64];                  // [wave/quarter][row]
    __shared__ float red[4];

    int m0  = blockIdx.x * 64;
    int tid = threadIdx.x;
    int lane = tid & 63, w = tid >> 6;
    int qbase = w * (KCODES / 4);
    int l15 = lane & 15, quad = lane >> 4;

    // ---- A prologue: ALL 64 block rows x 256 K fp32 -> fp8 in 64 VGPRs ----
    i32x8 A8[2][4];              // [kh(128-wide)][i-frag(16 rows)]
    #pragma unroll
    for (int kh = 0; kh < 2; kh++)
        #pragma unroll
        for (int i = 0; i < 4; i++) {
            const float* p = z + (size_t)(m0 + i * 16 + l15) * NDIM + kh * 128 + quad * 32;
            union { u32 u[8]; i32x8 v; } c;
            #pragma unroll
            for (int g = 0; g < 4; g++) {
                float4 x = *(const float4*)(p + g * 8);
                float4 y = *(const float4*)(p + g * 8 + 4);
                int r = __builtin_amdgcn_cvt_pk_fp8_f32(x.x, x.y, 0, false);
                r     = __builtin_amdgcn_cvt_pk_fp8_f32(x.z, x.w, r, true);
                c.u[g * 2] = (u32)r;
                r = __builtin_amdgcn_cvt_pk_fp8_f32(y.x, y.y, 0, false);
                r = __builtin_amdgcn_cvt_pk_fp8_f32(y.z, y.w, r, true);
                c.u[g * 2 + 1] = (u32)r;
            }
            A8[kh][i] = c.v;
        }
    // drain prologue loads so the raw vmcnt(12) below counts ONLY stage DMAs
    __asm__ volatile("s_waitcnt vmcnt(0)" ::: "memory");

    // ---- loop-invariant lane offsets (hoisted once; zero per-chunk VALU) ----
    // stage (4KB chunk): unit e = s2*64+lane in [0,256); plane pl = e>>7;
    //        e7 = e&127; r = e7>>2; stored su = e7&3 holds logical
    //        u = su^((r>>1)&3); global byte = r*256 + u*32 + pl*16
    int goff[4];
    #pragma unroll
    for (int s2 = 0; s2 < 4; s2++) {
        int e  = s2 * 64 + lane;
        int pl = e >> 7;
        int e7 = e & 127;
        int r  = e7 >> 2;
        int u  = (e7 & 3) ^ ((r >> 1) & 3);
        goff[s2] = r * NDIM + u * 32 + pl * 16;
    }
    // read: per j-frag, lane addr rb*64 + ((quad^((rb>>1)&3))<<4), planes +2048
    int roff[2];
    #pragma unroll
    for (int j = 0; j < 2; j++) {
        int rb = j * 16 + l15;
        roff[j] = rb * 64 + ((quad ^ ((rb >> 1) & 3)) << 4);
    }

    char* myB = &Bs[w][0][0];
    // chunk c (0..127): code group g=c>>1 (32 codes), K-half kh=c&1.
    // c>127 clamps to a harmless dead re-stage of chunk 127 (slot already dead).
    auto stage = [&](int slot, int c) {
        int cc = c > 127 ? 127 : c;
        const char* src = (const char*)cbb8 + (size_t)qbase * NDIM
                        + (size_t)(cc >> 1) * (32 * NDIM) + (cc & 1) * 128;
        char* dst = myB + slot * 4096;
        #pragma unroll
        for (int s2 = 0; s2 < 4; s2++)
            __builtin_amdgcn_global_load_lds((as1_void*)(src + goff[s2]),
                (as3_void*)(dst + (s2 * 64 + lane) * 16), 16, 0, 0);
    };

    const f32x4 bias4 = {2048.f, 2048.f, 2048.f, 2048.f};
    f32x4 acc[4][2];
    float mkey[16];
    #pragma unroll
    for (int s = 0; s < 16; s++) mkey[s] = 0.f;

    stage(0, 0); stage(1, 1); stage(2, 2);    // prime 3 chunks (12 DMAs)

    #pragma unroll 1
    for (int gg = 0; gg < 32; gg++) {
        #pragma unroll
        for (int h = 0; h < 2; h++) {          // g = gg*2+h; c = 2*g
            int g = gg * 2 + h;
            int c = g * 2;
            // ---- kh=0 chunk in slot 2h; prefetch chunk c+3 -> slot (2h+3)&3 ----
            stage((2 * h + 3) & 3, c + 3);
            __asm__ volatile("s_waitcnt vmcnt(12)" ::: "memory");   // chunk c resident
            {
                const char* sp = myB + (2 * h) * 4096;
                #pragma unroll
                for (int j = 0; j < 2; j++) {
                    union { int4 q[2]; i32x8 v; } u;
                    u.q[0] = *(const int4*)(sp + roff[j]);            // plane 0
                    u.q[1] = *(const int4*)(sp + 2048 + roff[j]);     // plane 1
                    #pragma unroll
                    for (int i = 0; i < 4; i++)
                        acc[i][j] = __builtin_amdgcn_mfma_scale_f32_16x16x128_f8f6f4(
                                        A8[0][i], u.v, bias4, 0, 0, 0, 0x7F7F7F7F, 0, 0x7F7F7F7F);
                }
            }
            // ---- kh=1 chunk in slot 2h+1; prefetch chunk c+4 -> slot 2h ----
            stage((2 * h) & 3, c + 4);
            __asm__ volatile("s_waitcnt vmcnt(12)" ::: "memory");   // chunk c+1 resident
            {
                const char* sp = myB + (2 * h + 1) * 4096;
                #pragma unroll
                for (int j = 0; j < 2; j++) {
                    union { int4 q[2]; i32x8 v; } u;
                    u.q[0] = *(const int4*)(sp + roff[j]);
                    u.q[1] = *(const int4*)(sp + 2048 + roff[j]);
                    #pragma unroll
                    for (int i = 0; i < 4; i++)
                        acc[i][j] = __builtin_amdgcn_mfma_scale_f32_16x16x128_f8f6f4(
                                        A8[1][i], u.v, acc[i][j], 0, 0, 0, 0x7F7F7F7F, 0, 0x7F7F7F7F);
                }
            }
            // packed-key argmax: 2 VALU/element (v_and_or_b32 + v_max_f32)
            int cb0 = qbase + g * 32 + l15;
            #pragma unroll
            for (int i = 0; i < 4; i++)
                #pragma unroll
                for (int r = 0; r < 4; r++) {
                    int s = i * 4 + r;
                    #pragma unroll
                    for (int j = 0; j < 2; j++) {
                        u32 p = (__float_as_uint(acc[i][j][r]) & 0xFFFFE000u) | (u32)(cb0 + j * 16);
                        mkey[s] = fmaxf(mkey[s], __uint_as_float(p));
                    }
                }
        }
    }

    // ---- merge: reduce over 16 col-lanes, stash per-row keys in LDS ----
    #pragma unroll
    for (int s = 0; s < 16; s++) {
        float v = mkey[s];
        #pragma unroll
        for (int sh = 1; sh < 16; sh <<= 1)
            v = fmaxf(v, __shfl_xor(v, sh, 64));
        if (l15 == s)    // one writer per 16-lane group (4 quads -> 4 rows)
            keys_lds[w][(s >> 2) * 16 + quad * 4 + (s & 3)] = __float_as_uint(v);
    }
    __syncthreads();

    // ---- fused gather + straight-through + loss (block's own 64 rows) ----
    int d = lane * 4;
    float sacc = 0.f;
    #pragma unroll
    for (int g = 0; g < 16; g++) {
        int rl = w * 16 + g;
        u32 k0 = keys_lds[0][rl], k1 = keys_lds[1][rl];
        u32 k2 = keys_lds[2][rl], k3 = keys_lds[3][rl];
        u32 a = k0 > k1 ? k0 : k1;
        u32 b = k2 > k3 ? k2 : k3;
        u32 idx = (a > b ? a : b) & 0x1FFFu;
        size_t zoff = (size_t)(m0 + rl) * NDIM + d;
        float4 zv = *(const float4*)(z + zoff);
        float4 qv = *(const float4*)(cb + (size_t)idx * NDIM + d);
        float4 o;
        o.x = zv.x + (qv.x - zv.x);           // straight-through, matches ref fp ops
        o.y = zv.y + (qv.y - zv.y);
        o.z = zv.z + (qv.z - zv.z);
        o.w = zv.w + (qv.w - zv.w);
        *(float4*)(out + zoff) = o;
        float dx = zv.x - qv.x, dy = zv.y - qv.y, dz = zv.z - qv.z, dw = zv.w - qv.w;
        sacc += dx * dx + dy * dy + dz * dz + dw * dw;
    }
    #pragma unroll
    for (int off = 32; off > 0; off >>= 1) sacc += __shfl_down(sacc, off, 64);
    if (lane == 0) red[w] = sacc;
    __syncthreads();
    if (tid == 0) {
        float tot = (red[0] + red[1]) + (red[2] + red[3]);
        atomicAdd(out + ND_TOT, tot * (1.25f / 8388608.f));   // (0.25+1.0)*mean
    }
}

extern "C" void kernel_launch(void* const* d_in, const int* in_sizes, int n_in,
                              void* d_out, int out_size, void* d_ws, size_t ws_size,
                              hipStream_t stream) {
    const float* z  = (const float*)d_in[0];   // 8*256*64*64 fp32
    const float* cb = (const float*)d_in[1];   // 8192*256 fp32
    float* out = (float*)d_out;                // 8388608 quantized_st + 1 loss

    u32* cbb8 = (u32*)d_ws;                    // 2 MB (cb fp8 * 8192)

    prep_cb8_kernel<<<KCODES * NDIM / 16 / 256, 256, 0, stream>>>(cb, cbb8, out + ND_TOT);
    vq_fused_kernel<<<NROWS / 64, 256, 0, stream>>>(z, cb, cbb8, out);
}

// Round 2
// 163.871 us; speedup vs baseline: 1.0354x; 1.0333x over previous
//
#include <hip/hip_runtime.h>
#include <stdint.h>

typedef unsigned int u32;

using i32x8 = __attribute__((ext_vector_type(8))) int;
using f32x4 = __attribute__((ext_vector_type(4))) float;

#define NROWS 32768   // B*H*W*D / 256 rows after reshape(-1,256)
#define NDIM  256
#define KCODES 8192
#define ND_TOT 8388608
#define CBSCALE 8192.0f   // lifts codebook (+-1.2e-4) into e4m3 range; argmax invariant

// ---------------- prep: cb -> fp8, repacked MFMA-fragment-contiguous ----------------
// Output unit u (16 bytes) <-> (T, kh, s, lane), byte addr = u*16 with
//   T = u>>8 (16-code tile), kh = (u>>7)&1 (K-half), s = (u>>6)&1, lane = u&63.
// Source floats: code = T*16 + (lane&15);
//   off = code*256 + kh*128 + (lane>>4)*32 + s*16   (16 consecutive floats).
// This is exactly the per-lane B-fragment byte order of
// mfma_scale_f32_16x16x128_f8f6f4 (lane holds code=l15, K bytes quad*32+[0,32)),
// so the runtime kernel's loads are wave-contiguous 1KB dwordx4 bursts.
// Each prep thread reads one 64B-aligned 64B block -> no overfetch.
__global__ __launch_bounds__(256) void prep_cb8_kernel(const float* __restrict__ cb,
                                                       u32* __restrict__ cbb8,
                                                       float* __restrict__ loss) {
    if (blockIdx.x == 0 && threadIdx.x == 0) loss[0] = 0.f;   // out re-poisoned each call
    int u = blockIdx.x * 256 + threadIdx.x;                   // 0..131071
    int T = u >> 8, rest = u & 255;
    int kh = rest >> 7, s = (rest >> 6) & 1, lane = rest & 63;
    int code = T * 16 + (lane & 15);
    const float* src = cb + (size_t)code * NDIM + kh * 128 + (lane >> 4) * 32 + s * 16;
    uint4 o;
    #pragma unroll
    for (int q = 0; q < 4; q++) {
        float4 v = *(const float4*)(src + q * 4);
        int r = __builtin_amdgcn_cvt_pk_fp8_f32(v.x * CBSCALE, v.y * CBSCALE, 0, false);
        r     = __builtin_amdgcn_cvt_pk_fp8_f32(v.z * CBSCALE, v.w * CBSCALE, r, true);
        ((u32*)&o)[q] = (u32)r;
    }
    *(uint4*)((char*)cbb8 + (size_t)u * 16) = o;
}

// ---------------- fully fused: GEMM + argmax + gather + ST + loss ----------------
// Block = 64 m-rows x ALL 8192 codes; grid 512 = 2 blocks/CU. Each of the 4
// waves holds ALL 64 rows in registers (A replicated) and owns a private
// codebook QUARTER (2048 codes = 128 16-code tiles).
//
// R2 change: the LDS staging ring is DELETED. R1 showed depth-1 -> depth-3
// changed nothing (100.5 -> 100.5 us, MfmaUtil 29%): the limiter was the
// serial DMA->LDS->reg->MFMA chain itself. The staged data was wave-private
// and read exactly once -- the LDS round-trip (~75k cyc/CU of LDS port time,
// equal to the whole MFMA budget) bought zero reuse. Now B fragments are
// loaded straight from the (L2-resident, fragment-contiguous) packed
// codebook into VGPRs: per tile, 4x global_load_dwordx4, each a fully
// coalesced 1KB burst. 4 register buffers, 3-tile-deep prefetch; the
// compiler's per-register vmcnt scoreboard handles the waits. No barriers,
// no LDS in the loop at all.
//
// acc-init eliminated via bias-C on the kh=0 MFMA (+2048 => scores positive
// => float order == int order). Packed-key argmax unchanged. After the loop:
// one __syncthreads, merge 4 quarter-keys in LDS (1KB), gather fp32 codebook
// rows, straight-through write + one atomicAdd loss partial.
__global__ __launch_bounds__(256, 2) void vq_fused_kernel(const float* __restrict__ z,
                                                          const float* __restrict__ cb,
                                                          const u32* __restrict__ cbb8,
                                                          float* __restrict__ out) {
    __shared__ u32 keys_lds[4][64];                  // [wave/quarter][row]
    __shared__ float red[4];

    int m0  = blockIdx.x * 64;
    int tid = threadIdx.x;
    int lane = tid & 63, w = tid >> 6;
    int qbase = w * (KCODES / 4);
    int l15 = lane & 15, quad = lane >> 4;

    // ---- A prologue: ALL 64 block rows x 256 K fp32 -> fp8 in 64 VGPRs ----
    i32x8 A8[2][4];              // [kh(128-wide)][i-frag(16 rows)]
    #pragma unroll
    for (int kh = 0; kh < 2; kh++)
        #pragma unroll
        for (int i = 0; i < 4; i++) {
            const float* p = z + (size_t)(m0 + i * 16 + l15) * NDIM + kh * 128 + quad * 32;
            union { u32 u[8]; i32x8 v; } c;
            #pragma unroll
            for (int g = 0; g < 4; g++) {
                float4 x = *(const float4*)(p + g * 8);
                float4 y = *(const float4*)(p + g * 8 + 4);
                int r = __builtin_amdgcn_cvt_pk_fp8_f32(x.x, x.y, 0, false);
                r     = __builtin_amdgcn_cvt_pk_fp8_f32(x.z, x.w, r, true);
                c.u[g * 2] = (u32)r;
                r = __builtin_amdgcn_cvt_pk_fp8_f32(y.x, y.y, 0, false);
                r = __builtin_amdgcn_cvt_pk_fp8_f32(y.z, y.w, r, true);
                c.u[g * 2 + 1] = (u32)r;
            }
            A8[kh][i] = c.v;
        }

    // ---- B stream: packed fragment layout, per-lane base + tile offsets ----
    // tile n of wave w lives at bytes (w*128 + n)*4096; lane slice = +lane*16.
    // pieces (kh,s) at +0 / +1024 / +2048 / +3072 bytes = +0/64/128/192 int4.
    const int4* lp = (const int4*)((const char*)cbb8
                     + (size_t)(w * 128) * 4096 + (size_t)lane * 16);

    auto loadt = [&](int4* dst, int n) {
        int nn = n > 127 ? 127 : n;          // tail prefetches: dead re-load of 127
        const int4* p = lp + (size_t)nn * 256;
        dst[0] = p[0];
        dst[1] = p[64];
        dst[2] = p[128];
        dst[3] = p[192];
    };

    const f32x4 bias4 = {2048.f, 2048.f, 2048.f, 2048.f};
    float mkey[16];
    #pragma unroll
    for (int s = 0; s < 16; s++) mkey[s] = 0.f;

    auto proc = [&](const int4* b, int n) {
        union { int4 q[2]; i32x8 v; } u0, u1;
        u0.q[0] = b[0]; u0.q[1] = b[1];      // kh=0 fragment (32B/lane)
        u1.q[0] = b[2]; u1.q[1] = b[3];      // kh=1 fragment
        f32x4 acc[4];
        #pragma unroll
        for (int i = 0; i < 4; i++)
            acc[i] = __builtin_amdgcn_mfma_scale_f32_16x16x128_f8f6f4(
                         A8[0][i], u0.v, bias4, 0, 0, 0, 0x7F7F7F7F, 0, 0x7F7F7F7F);
        #pragma unroll
        for (int i = 0; i < 4; i++)
            acc[i] = __builtin_amdgcn_mfma_scale_f32_16x16x128_f8f6f4(
                         A8[1][i], u1.v, acc[i], 0, 0, 0, 0x7F7F7F7F, 0, 0x7F7F7F7F);
        // packed-key argmax: 2 VALU/element (v_and_or_b32 + v_max_f32)
        int cb0 = qbase + n * 16 + l15;
        #pragma unroll
        for (int i = 0; i < 4; i++)
            #pragma unroll
            for (int r = 0; r < 4; r++) {
                u32 p = (__float_as_uint(acc[i][r]) & 0xFFFFE000u) | (u32)cb0;
                mkey[i * 4 + r] = fmaxf(mkey[i * 4 + r], __uint_as_float(p));
            }
    };

    // ---- main loop: 128 tiles, 4 reg buffers, 3-deep prefetch ----
    int4 bb0[4], bb1[4], bb2[4], bb3[4];
    loadt(bb0, 0); loadt(bb1, 1); loadt(bb2, 2);

    #pragma unroll 1
    for (int n = 0; n < 128; n += 4) {
        loadt(bb3, n + 3);
        proc(bb0, n + 0);
        loadt(bb0, n + 4);
        proc(bb1, n + 1);
        loadt(bb1, n + 5);
        proc(bb2, n + 2);
        loadt(bb2, n + 6);
        proc(bb3, n + 3);
    }

    // ---- merge: reduce over 16 col-lanes, stash per-row keys in LDS ----
    #pragma unroll
    for (int s = 0; s < 16; s++) {
        float v = mkey[s];
        #pragma unroll
        for (int sh = 1; sh < 16; sh <<= 1)
            v = fmaxf(v, __shfl_xor(v, sh, 64));
        if (l15 == s)    // one writer per 16-lane group (4 quads -> 4 rows)
            keys_lds[w][(s >> 2) * 16 + quad * 4 + (s & 3)] = __float_as_uint(v);
    }
    __syncthreads();

    // ---- fused gather + straight-through + loss (block's own 64 rows) ----
    int d = lane * 4;
    float sacc = 0.f;
    #pragma unroll
    for (int g = 0; g < 16; g++) {
        int rl = w * 16 + g;
        u32 k0 = keys_lds[0][rl], k1 = keys_lds[1][rl];
        u32 k2 = keys_lds[2][rl], k3 = keys_lds[3][rl];
        u32 a = k0 > k1 ? k0 : k1;
        u32 b = k2 > k3 ? k2 : k3;
        u32 idx = (a > b ? a : b) & 0x1FFFu;
        size_t zoff = (size_t)(m0 + rl) * NDIM + d;
        float4 zv = *(const float4*)(z + zoff);
        float4 qv = *(const float4*)(cb + (size_t)idx * NDIM + d);
        float4 o;
        o.x = zv.x + (qv.x - zv.x);           // straight-through, matches ref fp ops
        o.y = zv.y + (qv.y - zv.y);
        o.z = zv.z + (qv.z - zv.z);
        o.w = zv.w + (qv.w - zv.w);
        *(float4*)(out + zoff) = o;
        float dx = zv.x - qv.x, dy = zv.y - qv.y, dz = zv.z - qv.z, dw = zv.w - qv.w;
        sacc += dx * dx + dy * dy + dz * dz + dw * dw;
    }
    #pragma unroll
    for (int off = 32; off > 0; off >>= 1) sacc += __shfl_down(sacc, off, 64);
    if (lane == 0) red[w] = sacc;
    __syncthreads();
    if (tid == 0) {
        float tot = (red[0] + red[1]) + (red[2] + red[3]);
        atomicAdd(out + ND_TOT, tot * (1.25f / 8388608.f));   // (0.25+1.0)*mean
    }
}

extern "C" void kernel_launch(void* const* d_in, const int* in_sizes, int n_in,
                              void* d_out, int out_size, void* d_ws, size_t ws_size,
                              hipStream_t stream) {
    const float* z  = (const float*)d_in[0];   // 8*256*64*64 fp32
    const float* cb = (const float*)d_in[1];   // 8192*256 fp32
    float* out = (float*)d_out;                // 8388608 quantized_st + 1 loss

    u32* cbb8 = (u32*)d_ws;                    // 2 MB (cb fp8, fragment-packed)

    prep_cb8_kernel<<<KCODES * NDIM / 16 / 256, 256, 0, stream>>>(cb, cbb8, out + ND_TOT);
    vq_fused_kernel<<<NROWS / 64, 256, 0, stream>>>(z, cb, cbb8, out);
}

// Round 6
// 153.198 us; speedup vs baseline: 1.1075x; 1.0697x over previous
//
#include <hip/hip_runtime.h>
#include <stdint.h>

typedef unsigned int u32;

using i32x8 = __attribute__((ext_vector_type(8))) int;
using f32x4 = __attribute__((ext_vector_type(4))) float;

#define NROWS 32768   // B*H*W*D / 256 rows after reshape(-1,256)
#define NDIM  256
#define KCODES 8192
#define ND_TOT 8388608
#define CBSCALE 8192.0f   // lifts codebook (+-1.2e-4) into e4m3 range; argmax invariant

// ---------------- prep: cb -> fp8, repacked MFMA-fragment-contiguous ----------------
// Output unit u (16 bytes) <-> (T, kh, s, lane), byte addr = u*16 with
//   T = u>>8 (16-code tile), kh = (u>>7)&1 (K-half), s = (u>>6)&1, lane = u&63.
// Source floats: code = T*16 + (lane&15);
//   off = code*256 + kh*128 + (lane>>4)*32 + s*16   (16 consecutive floats).
// Exactly the per-lane B-fragment byte order of mfma_scale_f32_16x16x128_f8f6f4,
// so the runtime kernel's loads are wave-contiguous 1KB dwordx4 bursts.
__global__ __launch_bounds__(256) void prep_cb8_kernel(const float* __restrict__ cb,
                                                       u32* __restrict__ cbb8,
                                                       float* __restrict__ loss) {
    if (blockIdx.x == 0 && threadIdx.x == 0) loss[0] = 0.f;   // out re-poisoned each call
    int u = blockIdx.x * 256 + threadIdx.x;                   // 0..131071
    int T = u >> 8, rest = u & 255;
    int kh = rest >> 7, s = (rest >> 6) & 1, lane = rest & 63;
    int code = T * 16 + (lane & 15);
    const float* src = cb + (size_t)code * NDIM + kh * 128 + (lane >> 4) * 32 + s * 16;
    uint4 o;
    #pragma unroll
    for (int q = 0; q < 4; q++) {
        float4 v = *(const float4*)(src + q * 4);
        int r = __builtin_amdgcn_cvt_pk_fp8_f32(v.x * CBSCALE, v.y * CBSCALE, 0, false);
        r     = __builtin_amdgcn_cvt_pk_fp8_f32(v.z * CBSCALE, v.w * CBSCALE, r, true);
        ((u32*)&o)[q] = (u32)r;
    }
    *(uint4*)((char*)cbb8 + (size_t)u * 16) = o;
}

// ---------------- fully fused: GEMM + argmax + gather + ST + loss ----------------
// Block = 64 m-rows x ALL 8192 codes; grid 512 = 2 blocks/CU. Each of the 4
// waves holds ALL 64 rows in registers (A replicated) and owns a private
// codebook QUARTER (2048 codes = 128 16-code tiles) streamed from L2.
//
// R6 = R5's ISA-forced register pipeline + EARLY-CLOBBER load outputs.
// R5 compiled but aborted at runtime: with plain "=v" outputs the register
// allocator may overlap an output quad with the %4 address pair (asm
// outputs are "written at the end"), but global_load is ASYNC -- returning
// data clobbers the address while later loads still need it -> wild 64-bit
// address -> GPU memory fault -> abort. "=&v" (early-clobber) forbids
// output/input overlap; r282 confirms it compiles on this toolchain.
// Mechanism recap (R2's VGPR=104 proved the C-level pipeline collapsed,
// exposing ~600cyc L2 latency per 277cyc tile-proc -> MfmaUtil 29%):
//   - B-tile loads: asm volatile global_load_dwordx4 x4 (one base addr,
//     offset:0/1024/2048/3072) -> issue order pinned; outputs are asm-defined
//     values consumed 3 phases later, so the allocator MUST keep 4 buffers.
//   - before consuming a buffer: asm "s_waitcnt vmcnt(N)" +
//     __builtin_amdgcn_sched_barrier(0) -- stops register-only MFMAs
//     hoisting above the wait (guide rule #18).
//   - main loop tiles 0..123 (steady vmcnt(12)); peeled epilogue issues
//     tile 127's load then descending waits 12/8/4/0. Every load consumed
//     -> no in-flight writes into reusable regs, no keep-alive asm needed.
// Steady state: issue distance = 3 procs (~1000cyc) >> L2 latency; next
// walls are the L2 codebook stream (4MB/CU ~75k cyc) and the MFMA floor
// (~71k cyc), i.e. ~33us.
//
// acc-init eliminated via bias-C on the kh=0 MFMA (+2048 => scores positive
// => float order == int order). Packed-key argmax: 2 VALU/element. After the
// loop: merge 4 quarter-keys in LDS (1KB), gather fp32 codebook rows,
// straight-through write + one atomicAdd loss partial.
__global__ __launch_bounds__(256, 2) void vq_fused_kernel(const float* __restrict__ z,
                                                          const float* __restrict__ cb,
                                                          const u32* __restrict__ cbb8,
                                                          float* __restrict__ out) {
    __shared__ u32 keys_lds[4][64];                  // [wave/quarter][row]
    __shared__ float red[4];

    int m0  = blockIdx.x * 64;
    int tid = threadIdx.x;
    int lane = tid & 63, w = tid >> 6;
    int qbase = w * (KCODES / 4);
    int l15 = lane & 15, quad = lane >> 4;

    // ---- A prologue: ALL 64 block rows x 256 K fp32 -> fp8 in 64 VGPRs ----
    i32x8 A8[2][4];              // [kh(128-wide)][i-frag(16 rows)]
    #pragma unroll
    for (int kh = 0; kh < 2; kh++)
        #pragma unroll
        for (int i = 0; i < 4; i++) {
            const float* p = z + (size_t)(m0 + i * 16 + l15) * NDIM + kh * 128 + quad * 32;
            union { u32 u[8]; i32x8 v; } c;
            #pragma unroll
            for (int g = 0; g < 4; g++) {
                float4 x = *(const float4*)(p + g * 8);
                float4 y = *(const float4*)(p + g * 8 + 4);
                int r = __builtin_amdgcn_cvt_pk_fp8_f32(x.x, x.y, 0, false);
                r     = __builtin_amdgcn_cvt_pk_fp8_f32(x.z, x.w, r, true);
                c.u[g * 2] = (u32)r;
                r = __builtin_amdgcn_cvt_pk_fp8_f32(y.x, y.y, 0, false);
                r = __builtin_amdgcn_cvt_pk_fp8_f32(y.z, y.w, r, true);
                c.u[g * 2 + 1] = (u32)r;
            }
            A8[kh][i] = c.v;
        }
    // drain prologue loads so the raw vmcnt(N) below counts ONLY B-tile loads
    __asm__ volatile("s_waitcnt vmcnt(0)" ::: "memory");
    __builtin_amdgcn_sched_barrier(0);

    // ---- B stream: packed fragment layout, per-lane base + tile offsets ----
    // tile n of wave w lives at bytes (w*128 + n)*4096; lane slice = +lane*16.
    // pieces (kh,s) at byte offsets +0 / +1024 / +2048 / +3072.
    const char* lp = (const char*)cbb8 + (size_t)(w * 128) * 4096 + (size_t)lane * 16;

    auto loadt = [&](int4* b, int n) {
        const char* pa = lp + (size_t)n * 4096;
        asm volatile("global_load_dwordx4 %0, %4, off\n\t"
                     "global_load_dwordx4 %1, %4, off offset:1024\n\t"
                     "global_load_dwordx4 %2, %4, off offset:2048\n\t"
                     "global_load_dwordx4 %3, %4, off offset:3072"
                     : "=&v"(b[0]), "=&v"(b[1]), "=&v"(b[2]), "=&v"(b[3])
                     : "v"(pa));
    };
    // buffer-resident waits; sched_barrier stops consumers hoisting (rule #18)
    auto wait12 = [&]() { asm volatile("s_waitcnt vmcnt(12)" ::: "memory");
                          __builtin_amdgcn_sched_barrier(0); };
    auto wait8  = [&]() { asm volatile("s_waitcnt vmcnt(8)"  ::: "memory");
                          __builtin_amdgcn_sched_barrier(0); };
    auto wait4  = [&]() { asm volatile("s_waitcnt vmcnt(4)"  ::: "memory");
                          __builtin_amdgcn_sched_barrier(0); };
    auto wait0  = [&]() { asm volatile("s_waitcnt vmcnt(0)"  ::: "memory");
                          __builtin_amdgcn_sched_barrier(0); };

    const f32x4 bias4 = {2048.f, 2048.f, 2048.f, 2048.f};
    float mkey[16];
    #pragma unroll
    for (int s = 0; s < 16; s++) mkey[s] = 0.f;

    auto proc = [&](const int4* b, int n) {
        union { int4 q[2]; i32x8 v; } u0, u1;
        u0.q[0] = b[0]; u0.q[1] = b[1];      // kh=0 fragment (32B/lane)
        u1.q[0] = b[2]; u1.q[1] = b[3];      // kh=1 fragment
        f32x4 acc[4];
        #pragma unroll
        for (int i = 0; i < 4; i++)
            acc[i] = __builtin_amdgcn_mfma_scale_f32_16x16x128_f8f6f4(
                         A8[0][i], u0.v, bias4, 0, 0, 0, 0x7F7F7F7F, 0, 0x7F7F7F7F);
        #pragma unroll
        for (int i = 0; i < 4; i++)
            acc[i] = __builtin_amdgcn_mfma_scale_f32_16x16x128_f8f6f4(
                         A8[1][i], u1.v, acc[i], 0, 0, 0, 0x7F7F7F7F, 0, 0x7F7F7F7F);
        // packed-key argmax: 2 VALU/element (v_and_or_b32 + v_max_f32)
        int cb0 = qbase + n * 16 + l15;
        #pragma unroll
        for (int i = 0; i < 4; i++)
            #pragma unroll
            for (int r = 0; r < 4; r++) {
                u32 p = (__float_as_uint(acc[i][r]) & 0xFFFFE000u) | (u32)cb0;
                mkey[i * 4 + r] = fmaxf(mkey[i * 4 + r], __uint_as_float(p));
            }
    };

    // ---- main loop: tiles 0..123, 4 forced reg buffers, 3-tile-deep prefetch ----
    int4 bb0[4], bb1[4], bb2[4], bb3[4];
    loadt(bb0, 0); loadt(bb1, 1); loadt(bb2, 2);   // prime: 12 loads in flight

    #pragma unroll 1
    for (int n = 0; n < 124; n += 4) {
        loadt(bb3, n + 3);   wait12();  proc(bb0, n + 0);
        loadt(bb0, n + 4);   wait12();  proc(bb1, n + 1);
        loadt(bb1, n + 5);   wait12();  proc(bb2, n + 2);
        loadt(bb2, n + 6);   wait12();  proc(bb3, n + 3);
    }
    // ---- peeled tail: tiles 124..127, descending waits, zero dead loads ----
    loadt(bb3, 127);
    wait12();  proc(bb0, 124);
    wait8();   proc(bb1, 125);
    wait4();   proc(bb2, 126);
    wait0();   proc(bb3, 127);

    // ---- merge: reduce over 16 col-lanes, stash per-row keys in LDS ----
    #pragma unroll
    for (int s = 0; s < 16; s++) {
        float v = mkey[s];
        #pragma unroll
        for (int sh = 1; sh < 16; sh <<= 1)
            v = fmaxf(v, __shfl_xor(v, sh, 64));
        if (l15 == s)    // one writer per 16-lane group (4 quads -> 4 rows)
            keys_lds[w][(s >> 2) * 16 + quad * 4 + (s & 3)] = __float_as_uint(v);
    }
    __syncthreads();

    // ---- fused gather + straight-through + loss (block's own 64 rows) ----
    int d = lane * 4;
    float sacc = 0.f;
    #pragma unroll
    for (int g = 0; g < 16; g++) {
        int rl = w * 16 + g;
        u32 k0 = keys_lds[0][rl], k1 = keys_lds[1][rl];
        u32 k2 = keys_lds[2][rl], k3 = keys_lds[3][rl];
        u32 a = k0 > k1 ? k0 : k1;
        u32 b = k2 > k3 ? k2 : k3;
        u32 idx = (a > b ? a : b) & 0x1FFFu;
        size_t zoff = (size_t)(m0 + rl) * NDIM + d;
        float4 zv = *(const float4*)(z + zoff);
        float4 qv = *(const float4*)(cb + (size_t)idx * NDIM + d);
        float4 o;
        o.x = zv.x + (qv.x - zv.x);           // straight-through, matches ref fp ops
        o.y = zv.y + (qv.y - zv.y);
        o.z = zv.z + (qv.z - zv.z);
        o.w = zv.w + (qv.w - zv.w);
        *(float4*)(out + zoff) = o;
        float dx = zv.x - qv.x, dy = zv.y - qv.y, dz = zv.z - qv.z, dw = zv.w - qv.w;
        sacc += dx * dx + dy * dy + dz * dz + dw * dw;
    }
    #pragma unroll
    for (int off = 32; off > 0; off >>= 1) sacc += __shfl_down(sacc, off, 64);
    if (lane == 0) red[w] = sacc;
    __syncthreads();
    if (tid == 0) {
        float tot = (red[0] + red[1]) + (red[2] + red[3]);
        atomicAdd(out + ND_TOT, tot * (1.25f / 8388608.f));   // (0.25+1.0)*mean
    }
}

extern "C" void kernel_launch(void* const* d_in, const int* in_sizes, int n_in,
                              void* d_out, int out_size, void* d_ws, size_t ws_size,
                              hipStream_t stream) {
    const float* z  = (const float*)d_in[0];   // 8*256*64*64 fp32
    const float* cb = (const float*)d_in[1];   // 8192*256 fp32
    float* out = (float*)d_out;                // 8388608 quantized_st + 1 loss

    u32* cbb8 = (u32*)d_ws;                    // 2 MB (cb fp8, fragment-packed)

    prep_cb8_kernel<<<KCODES * NDIM / 16 / 256, 256, 0, stream>>>(cb, cbb8, out + ND_TOT);
    vq_fused_kernel<<<NROWS / 64, 256, 0, stream>>>(z, cb, cbb8, out);
}